// Round 1
// baseline (142.219 us; speedup 1.0000x reference)
//
#include <hip/hip_runtime.h>
#include <hip/hip_bf16.h>

// BallPredictorGNN: 2-layer GAT + MLP head, but output depends ONLY on node N-1.
// Strategy: prune to the 2-hop incoming neighborhood of node N-1.
//   S1 = in-neighbors of ball (+ ball itself)   [~65 nodes]
//   S2 = in-neighbors of S1 (+ S1, self-loops)  [~1100 nodes]
// Layer-1 GAT computed only for dst in S1 (needs h1/alpha for S2).
// Layer-2 GAT computed only for dst = ball (needs h2/alpha for S1).

#define NEG_SLOPE 0.2f
constexpr int F_IN  = 128;
constexpr int HEADS = 4;
constexpr int CH    = 64;
constexpr int D1    = 256;   // HEADS*CH

constexpr int CAP1  = 512;    // |S1| cap (expected ~65)
constexpr int CAP2  = 4096;   // |S2| cap (expected ~1100)
constexpr int CAPE0 = 2048;   // ball in-edge cap (expected ~32)
constexpr int CAPP  = 32768;  // S1 in-edge (pair) cap (expected ~2100)

struct Ws {
    int* meta;    // [0]=count1 [1]=count2 [2]=cntE0 [3]=cntPairs
    int* flag1;   // [N]
    int* flag2;   // [N]
    int* inv1;    // [N] node -> idx in list1 (valid iff flag1)
    int* inv2;    // [N] node -> idx in list2 (valid iff flag2)
    int* list1;   // [CAP1]
    int* list2;   // [CAP2]
    int* e0;      // [CAPE0] srcs of edges into ball
    int* pairs;   // [2*CAPP] (dstIdx1, srcNode)
    float* H1c;   // [CAP2*D1]   h1 = x@W1 for S2 nodes
    float* as1;   // [CAP2*HEADS]
    float* ad1;   // [CAP2*HEADS]
    float* O1c;   // [CAP1*D1]   relu(layer1 out + b1) for S1 nodes
    float* h2c;   // [CAP1*CH]   relu(O1)@W2
    float* as2;   // [CAP1]
    float* ad2;   // [CAP1]
};

__global__ void k0_init(Ws w, int N, int ball) {
    int i = blockIdx.x * blockDim.x + threadIdx.x;
    if (i < N) {
        w.flag1[i] = (i == ball) ? 1 : 0;
        w.flag2[i] = 0;
        if (i == ball) w.inv1[i] = 0;
    }
    if (i == 0) {
        w.meta[0] = 1;  // count1: ball pre-inserted
        w.meta[1] = 0;
        w.meta[2] = 0;
        w.meta[3] = 0;
        w.list1[0] = ball;
    }
}

// scan edges for dst == ball; build S1
__global__ void k1_ball_edges(Ws w, const int* __restrict__ src,
                              const int* __restrict__ dst, int E, int ball) {
    int e = blockIdx.x * blockDim.x + threadIdx.x;
    if (e >= E) return;
    if (dst[e] == ball) {
        int s = src[e];
        int p = atomicAdd(&w.meta[2], 1);
        if (p < CAPE0) w.e0[p] = s;
        if (atomicExch(&w.flag1[s], 1) == 0) {
            int q = atomicAdd(&w.meta[0], 1);
            if (q < CAP1) { w.list1[q] = s; w.inv1[s] = q; }
        }
    }
}

// insert S1 nodes into S2 and append their self-loop pairs
__global__ void k1b_selfloops(Ws w) {
    int t = blockIdx.x * blockDim.x + threadIdx.x;
    int c1 = min(w.meta[0], CAP1);
    if (t >= c1) return;
    int v = w.list1[t];
    if (atomicExch(&w.flag2[v], 1) == 0) {
        int q = atomicAdd(&w.meta[1], 1);
        if (q < CAP2) { w.list2[q] = v; w.inv2[v] = q; }
    }
    int p = atomicAdd(&w.meta[3], 1);
    if (p < CAPP) { w.pairs[2 * p] = t; w.pairs[2 * p + 1] = v; }
}

// scan edges for dst in S1; collect (dstIdx, src) pairs; build S2
__global__ void k2_l1_edges(Ws w, const int* __restrict__ src,
                            const int* __restrict__ dst, int E) {
    int e = blockIdx.x * blockDim.x + threadIdx.x;
    if (e >= E) return;
    int d = dst[e];
    if (w.flag1[d]) {
        int s = src[e];
        int di = w.inv1[d];
        int p = atomicAdd(&w.meta[3], 1);
        if (p < CAPP) { w.pairs[2 * p] = di; w.pairs[2 * p + 1] = s; }
        if (atomicExch(&w.flag2[s], 1) == 0) {
            int q = atomicAdd(&w.meta[1], 1);
            if (q < CAP2) { w.list2[q] = s; w.inv2[s] = q; }
        }
    }
}

// h1 = x@W1 for S2 nodes; alpha_s1/alpha_d1
__global__ __launch_bounds__(256) void k3_h1(Ws w, const float* __restrict__ x,
                                             const float* __restrict__ W1,
                                             const float* __restrict__ a_s,
                                             const float* __restrict__ a_d) {
    int b = blockIdx.x;
    int c2 = min(w.meta[1], CAP2);
    if (b >= c2) return;
    int v = w.list2[b];
    __shared__ float xs[F_IN];
    int j = threadIdx.x;
    if (j < F_IN) xs[j] = x[(size_t)v * F_IN + j];
    __syncthreads();
    float acc = 0.f;
#pragma unroll 8
    for (int k = 0; k < F_IN; k++) acc += xs[k] * W1[k * D1 + j];
    w.H1c[b * D1 + j] = acc;
    int hh = j >> 6, cc = j & 63;
    float vs = acc * a_s[hh * CH + cc];
    float vd = acc * a_d[hh * CH + cc];
    for (int o = 32; o > 0; o >>= 1) {
        vs += __shfl_xor(vs, o, 64);
        vd += __shfl_xor(vd, o, 64);
    }
    if (cc == 0) { w.as1[b * HEADS + hh] = vs; w.ad1[b * HEADS + hh] = vd; }
}

// layer-1 GAT aggregation for each dst in S1 (exact segment softmax)
__global__ __launch_bounds__(256) void k4_l1_agg(Ws w, const float* __restrict__ b1) {
    int b = blockIdx.x;
    int c1 = min(w.meta[0], CAP1);
    if (b >= c1) return;
    int d = w.list1[b];
    int i2d = w.inv2[d];
    int np = min(w.meta[3], CAPP);
    int tid = threadIdx.x;
    int wv = tid >> 6, ln = tid & 63;

    float ad[HEADS];
#pragma unroll
    for (int h = 0; h < HEADS; h++) ad[h] = w.ad1[i2d * HEADS + h];

    __shared__ float redm[4][HEADS];
    __shared__ float reds[4][HEADS];

    // pass A: per-head max
    float m[HEADS];
#pragma unroll
    for (int h = 0; h < HEADS; h++) m[h] = -1e30f;
    for (int p = tid; p < np; p += 256) {
        if (w.pairs[2 * p] == b) {
            int s = w.pairs[2 * p + 1];
            int i2 = w.inv2[s];
#pragma unroll
            for (int h = 0; h < HEADS; h++) {
                float e = w.as1[i2 * HEADS + h] + ad[h];
                e = e > 0.f ? e : NEG_SLOPE * e;
                m[h] = fmaxf(m[h], e);
            }
        }
    }
#pragma unroll
    for (int h = 0; h < HEADS; h++)
        for (int o = 32; o > 0; o >>= 1) m[h] = fmaxf(m[h], __shfl_xor(m[h], o, 64));
    if (ln == 0)
        for (int h = 0; h < HEADS; h++) redm[wv][h] = m[h];
    __syncthreads();
#pragma unroll
    for (int h = 0; h < HEADS; h++)
        m[h] = fmaxf(fmaxf(redm[0][h], redm[1][h]), fmaxf(redm[2][h], redm[3][h]));

    // pass B: per-head sum of exp(e - m)
    float ss[HEADS];
#pragma unroll
    for (int h = 0; h < HEADS; h++) ss[h] = 0.f;
    for (int p = tid; p < np; p += 256) {
        if (w.pairs[2 * p] == b) {
            int s = w.pairs[2 * p + 1];
            int i2 = w.inv2[s];
#pragma unroll
            for (int h = 0; h < HEADS; h++) {
                float e = w.as1[i2 * HEADS + h] + ad[h];
                e = e > 0.f ? e : NEG_SLOPE * e;
                ss[h] += expf(e - m[h]);
            }
        }
    }
#pragma unroll
    for (int h = 0; h < HEADS; h++)
        for (int o = 32; o > 0; o >>= 1) ss[h] += __shfl_xor(ss[h], o, 64);
    if (ln == 0)
        for (int h = 0; h < HEADS; h++) reds[wv][h] = ss[h];
    __syncthreads();
#pragma unroll
    for (int h = 0; h < HEADS; h++)
        ss[h] = reds[0][h] + reds[1][h] + reds[2][h] + reds[3][h];

    // pass C: weighted aggregation; wave wv handles head wv, lane ln = channel
    int h = wv, c = ln;
    float acc = 0.f;
    for (int p = 0; p < np; p++) {
        if (w.pairs[2 * p] == b) {
            int s = w.pairs[2 * p + 1];
            int i2 = w.inv2[s];
            float e = w.as1[i2 * HEADS + h] + ad[h];
            e = e > 0.f ? e : NEG_SLOPE * e;
            float wt = expf(e - m[h]);
            acc += wt * w.H1c[i2 * D1 + h * CH + c];
        }
    }
    float out = acc / (ss[h] + 1e-16f) + b1[h * CH + c];
    w.O1c[b * D1 + h * CH + c] = out > 0.f ? out : 0.f;
}

// h2 = relu(O1)@W2 for S1 nodes; alpha_s2/alpha_d2
__global__ __launch_bounds__(64) void k5_h2(Ws w, const float* __restrict__ W2,
                                            const float* __restrict__ a_s2,
                                            const float* __restrict__ a_d2) {
    int b = blockIdx.x;
    int c1 = min(w.meta[0], CAP1);
    if (b >= c1) return;
    __shared__ float o1[D1];
    int j = threadIdx.x;
    for (int k = j; k < D1; k += 64) o1[k] = w.O1c[b * D1 + k];
    __syncthreads();
    float acc = 0.f;
#pragma unroll 8
    for (int k = 0; k < D1; k++) acc += o1[k] * W2[k * CH + j];
    w.h2c[b * CH + j] = acc;
    float vs = acc * a_s2[j];
    float vd = acc * a_d2[j];
    for (int o = 32; o > 0; o >>= 1) {
        vs += __shfl_xor(vs, o, 64);
        vd += __shfl_xor(vd, o, 64);
    }
    if (j == 0) { w.as2[b] = vs; w.ad2[b] = vd; }
}

// ball-node layer-2 aggregation + MLP head
__global__ __launch_bounds__(64) void k6_final(Ws w, const float* __restrict__ b2,
                                               const float* __restrict__ fc1w,
                                               const float* __restrict__ fc1b,
                                               const float* __restrict__ fc2w,
                                               const float* __restrict__ fc2b,
                                               float* __restrict__ out, int ball) {
    int j = threadIdx.x;
    int ne = min(w.meta[2], CAPE0);
    float adv = w.ad2[0];  // inv1[ball] == 0

    float m = -1e30f;
    for (int i = j; i <= ne; i += 64) {
        int s = (i < ne) ? w.e0[i] : ball;
        float e = w.as2[w.inv1[s]] + adv;
        e = e > 0.f ? e : NEG_SLOPE * e;
        m = fmaxf(m, e);
    }
    for (int o = 32; o > 0; o >>= 1) m = fmaxf(m, __shfl_xor(m, o, 64));

    float ss = 0.f;
    for (int i = j; i <= ne; i += 64) {
        int s = (i < ne) ? w.e0[i] : ball;
        float e = w.as2[w.inv1[s]] + adv;
        e = e > 0.f ? e : NEG_SLOPE * e;
        ss += expf(e - m);
    }
    for (int o = 32; o > 0; o >>= 1) ss += __shfl_xor(ss, o, 64);

    // lane j = channel
    float acc = 0.f;
    for (int i = 0; i <= ne; i++) {
        int s = (i < ne) ? w.e0[i] : ball;
        int i1 = w.inv1[s];
        float e = w.as2[i1] + adv;
        e = e > 0.f ? e : NEG_SLOPE * e;
        float wt = expf(e - m);
        acc += wt * w.h2c[i1 * CH + j];
    }
    float bv = acc / (ss + 1e-16f) + b2[j];
    bv = bv > 0.f ? bv : 0.f;

    __shared__ float ball_v[CH];
    __shared__ float z[32];
    ball_v[j] = bv;
    __syncthreads();
    if (j < 32) {
        float a = fc1b[j];
        for (int c = 0; c < CH; c++) a += ball_v[c] * fc1w[c * 32 + j];
        z[j] = a > 0.f ? a : 0.f;
    }
    __syncthreads();
    if (j < 2) {
        float a = fc2b[j];
        for (int k = 0; k < 32; k++) a += z[k] * fc2w[k * 2 + j];
        out[j] = a;
    }
}

extern "C" void kernel_launch(void* const* d_in, const int* in_sizes, int n_in,
                              void* d_out, int out_size, void* d_ws, size_t ws_size,
                              hipStream_t stream) {
    const float* x    = (const float*)d_in[0];
    const int*   ei   = (const int*)d_in[1];
    const float* W1   = (const float*)d_in[2];
    const float* as1w = (const float*)d_in[3];
    const float* ad1w = (const float*)d_in[4];
    const float* b1   = (const float*)d_in[5];
    const float* W2   = (const float*)d_in[6];
    const float* as2w = (const float*)d_in[7];
    const float* ad2w = (const float*)d_in[8];
    const float* b2   = (const float*)d_in[9];
    const float* fc1w = (const float*)d_in[10];
    const float* fc1b = (const float*)d_in[11];
    const float* fc2w = (const float*)d_in[12];
    const float* fc2b = (const float*)d_in[13];

    int E = in_sizes[1] / 2;
    int N = in_sizes[0] / F_IN;
    int ball = N - 1;
    const int* srcA = ei;
    const int* dstA = ei + E;

    // carve workspace
    char* p = (char*)d_ws;
    auto carve = [&](size_t bytes) {
        void* r = (void*)p;
        p += (bytes + 255) & ~(size_t)255;
        return r;
    };
    Ws w;
    w.meta  = (int*)carve(16 * sizeof(int));
    w.flag1 = (int*)carve((size_t)N * sizeof(int));
    w.flag2 = (int*)carve((size_t)N * sizeof(int));
    w.inv1  = (int*)carve((size_t)N * sizeof(int));
    w.inv2  = (int*)carve((size_t)N * sizeof(int));
    w.list1 = (int*)carve(CAP1 * sizeof(int));
    w.list2 = (int*)carve(CAP2 * sizeof(int));
    w.e0    = (int*)carve(CAPE0 * sizeof(int));
    w.pairs = (int*)carve(2 * CAPP * sizeof(int));
    w.H1c   = (float*)carve((size_t)CAP2 * D1 * sizeof(float));
    w.as1   = (float*)carve((size_t)CAP2 * HEADS * sizeof(float));
    w.ad1   = (float*)carve((size_t)CAP2 * HEADS * sizeof(float));
    w.O1c   = (float*)carve((size_t)CAP1 * D1 * sizeof(float));
    w.h2c   = (float*)carve((size_t)CAP1 * CH * sizeof(float));
    w.as2   = (float*)carve(CAP1 * sizeof(float));
    w.ad2   = (float*)carve(CAP1 * sizeof(float));

    int gE = (E + 255) / 256;
    k0_init<<<(N + 255) / 256, 256, 0, stream>>>(w, N, ball);
    k1_ball_edges<<<gE, 256, 0, stream>>>(w, srcA, dstA, E, ball);
    k1b_selfloops<<<CAP1 / 256, 256, 0, stream>>>(w);
    k2_l1_edges<<<gE, 256, 0, stream>>>(w, srcA, dstA, E);
    k3_h1<<<CAP2, 256, 0, stream>>>(w, x, W1, as1w, ad1w);
    k4_l1_agg<<<CAP1, 256, 0, stream>>>(w, b1);
    k5_h2<<<CAP1, 64, 0, stream>>>(w, W2, as2w, ad2w);
    k6_final<<<1, 64, 0, stream>>>(w, b2, fc1w, fc1b, fc2w, fc2b, (float*)d_out, ball);
}

// Round 2
// 66.084 us; speedup vs baseline: 2.1521x; 2.1521x over previous
//
#include <hip/hip_runtime.h>
#include <hip/hip_bf16.h>

// BallPredictorGNN: 2-layer GAT + MLP head; output depends ONLY on node N-1.
// Prune to the 2-hop incoming neighborhood of the ball node.
//   S1 = in-neighbors of ball (+ ball)          [~65 nodes]
//   S2 = in-neighbors of S1 (+ S1 self-loops)   [~1100 nodes]
// Edges into S1 are bucketed by dst (CSR-ish) so the per-dst softmax/agg
// kernel touches only its own ~33 edges (was: scan of all pairs -> 80us).

#define NEG_SLOPE 0.2f
constexpr int F_IN  = 128;
constexpr int HEADS = 4;
constexpr int CH    = 64;
constexpr int D1    = 256;   // HEADS*CH

constexpr int CAP1   = 512;   // |S1| cap (expected ~65)
constexpr int CAP2   = 4096;  // |S2| cap (expected ~1100)
constexpr int CAPE0  = 2048;  // ball in-edge cap (expected ~32)
constexpr int MAXDEG = 256;   // per-S1-node in-degree cap (expected ~33)

struct Ws {
    int* meta;    // [0]=count1 [1]=count2 [2]=cntE0
    int* flag1;   // [N]
    int* flag2;   // [N]
    int* inv1;    // [N]
    int* inv2;    // [N]
    int* list1;   // [CAP1]
    int* list2;   // [CAP2]
    int* e0;      // [CAPE0] srcs of edges into ball
    int* deg;     // [CAP1]  per-dst edge count
    int* nbr;     // [CAP1*MAXDEG] per-dst src-node buckets
    float* H1c;   // [CAP2*D1]    h1 = x@W1 for S2 nodes
    float* as1;   // [CAP2*HEADS]
    float* ad1;   // [CAP2*HEADS]
    float* h2c;   // [CAP1*CH]    relu(layer1)@W2
    float* as2;   // [CAP1]
    float* ad2;   // [CAP1]
};

__global__ void k0_init(Ws w, int N, int ball) {
    int i = blockIdx.x * blockDim.x + threadIdx.x;
    if (i < N) {
        w.flag1[i] = (i == ball) ? 1 : 0;
        w.flag2[i] = 0;
        if (i == ball) w.inv1[i] = 0;
    }
    if (i < CAP1) w.deg[i] = 0;
    if (i == 0) {
        w.meta[0] = 1;  // ball pre-inserted into S1
        w.meta[1] = 0;
        w.meta[2] = 0;
        w.list1[0] = ball;
    }
}

// scan edges for dst == ball; build S1 (int4-vectorized over edges)
__global__ void k1_ball_edges(Ws w, const int* __restrict__ src,
                              const int* __restrict__ dst, int E, int ball) {
    int t = blockIdx.x * blockDim.x + threadIdx.x;
    int e0 = t * 4;
    if (e0 >= E) return;
    int4 dv = *(const int4*)&dst[e0];
    int dd[4] = {dv.x, dv.y, dv.z, dv.w};
#pragma unroll
    for (int k = 0; k < 4; k++) {
        int e = e0 + k;
        if (e < E && dd[k] == ball) {
            int s = src[e];
            int p = atomicAdd(&w.meta[2], 1);
            if (p < CAPE0) w.e0[p] = s;
            if (atomicExch(&w.flag1[s], 1) == 0) {
                int q = atomicAdd(&w.meta[0], 1);
                if (q < CAP1) { w.list1[q] = s; w.inv1[s] = q; }
            }
        }
    }
}

// insert S1 nodes into S2 and append their self-loop edges to the buckets
__global__ void k1b_selfloops(Ws w) {
    int t = blockIdx.x * blockDim.x + threadIdx.x;
    int c1 = min(w.meta[0], CAP1);
    if (t >= c1) return;
    int v = w.list1[t];
    if (atomicExch(&w.flag2[v], 1) == 0) {
        int q = atomicAdd(&w.meta[1], 1);
        if (q < CAP2) { w.list2[q] = v; w.inv2[v] = q; }
    }
    int p = atomicAdd(&w.deg[t], 1);
    if (p < MAXDEG) w.nbr[t * MAXDEG + p] = v;
}

// scan edges for dst in S1; bucket by dst; build S2
__global__ void k2_l1_edges(Ws w, const int* __restrict__ src,
                            const int* __restrict__ dst, int E) {
    int t = blockIdx.x * blockDim.x + threadIdx.x;
    int e0 = t * 4;
    if (e0 >= E) return;
    int4 dv = *(const int4*)&dst[e0];
    int dd[4] = {dv.x, dv.y, dv.z, dv.w};
#pragma unroll
    for (int k = 0; k < 4; k++) {
        int e = e0 + k;
        if (e < E && w.flag1[dd[k]]) {
            int s = src[e];
            int di = w.inv1[dd[k]];
            int p = atomicAdd(&w.deg[di], 1);
            if (p < MAXDEG) w.nbr[di * MAXDEG + p] = s;
            if (atomicExch(&w.flag2[s], 1) == 0) {
                int q = atomicAdd(&w.meta[1], 1);
                if (q < CAP2) { w.list2[q] = s; w.inv2[s] = q; }
            }
        }
    }
}

// h1 = x@W1 for S2 nodes; alpha_s1/alpha_d1
__global__ __launch_bounds__(256) void k3_h1(Ws w, const float* __restrict__ x,
                                             const float* __restrict__ W1,
                                             const float* __restrict__ a_s,
                                             const float* __restrict__ a_d) {
    int b = blockIdx.x;
    int c2 = min(w.meta[1], CAP2);
    if (b >= c2) return;
    int v = w.list2[b];
    __shared__ float xs[F_IN];
    int j = threadIdx.x;
    if (j < F_IN) xs[j] = x[(size_t)v * F_IN + j];
    __syncthreads();
    float acc = 0.f;
#pragma unroll 8
    for (int k = 0; k < F_IN; k++) acc += xs[k] * W1[k * D1 + j];
    w.H1c[b * D1 + j] = acc;
    int hh = j >> 6, cc = j & 63;
    float vs = acc * a_s[hh * CH + cc];
    float vd = acc * a_d[hh * CH + cc];
    for (int o = 32; o > 0; o >>= 1) {
        vs += __shfl_xor(vs, o, 64);
        vd += __shfl_xor(vd, o, 64);
    }
    if (cc == 0) { w.as1[b * HEADS + hh] = vs; w.ad1[b * HEADS + hh] = vd; }
}

// layer-1 GAT aggregation for each dst in S1 (bucketed edges) FUSED with
// h2 = relu(out)@W2 and the alpha_s2/alpha_d2 reduction (block b is the
// only producer AND only consumer of row b).
__global__ __launch_bounds__(256) void k45_agg_h2(Ws w, const float* __restrict__ b1,
                                                  const float* __restrict__ W2,
                                                  const float* __restrict__ a_s2,
                                                  const float* __restrict__ a_d2) {
    int b = blockIdx.x;
    int c1 = min(w.meta[0], CAP1);
    if (b >= c1) return;
    int d = w.list1[b];
    int i2d = w.inv2[d];
    int deg = min(w.deg[b], MAXDEG);
    int tid = threadIdx.x;

    __shared__ int   sI2[MAXDEG];
    __shared__ float sW[MAXDEG][HEADS];   // e-values, then exp-weights
    __shared__ float sSum[HEADS];
    __shared__ float sO1[D1];

    for (int p = tid; p < deg; p += 256) sI2[p] = w.inv2[w.nbr[b * MAXDEG + p]];
    __syncthreads();

    // e per (edge, head)
    for (int t = tid; t < deg * HEADS; t += 256) {
        int p = t >> 2, h = t & 3;
        float e = w.as1[sI2[p] * HEADS + h] + w.ad1[i2d * HEADS + h];
        sW[p][h] = e > 0.f ? e : NEG_SLOPE * e;
    }
    __syncthreads();

    // per-head max -> exp -> sum (deg ~33, serial per head is trivial)
    if (tid < HEADS) {
        float m = -1e30f;
        for (int p = 0; p < deg; p++) m = fmaxf(m, sW[p][tid]);
        float s = 0.f;
        for (int p = 0; p < deg; p++) {
            float wt = expf(sW[p][tid] - m);
            sW[p][tid] = wt;
            s += wt;
        }
        sSum[tid] = s;
    }
    __syncthreads();

    // aggregate: wave h, lane = channel c; coalesced H1c reads
    int h = tid >> 6, c = tid & 63;
    float acc = 0.f;
    for (int p = 0; p < deg; p++)
        acc += sW[p][h] * w.H1c[sI2[p] * D1 + h * CH + c];
    float out = acc / (sSum[h] + 1e-16f) + b1[h * CH + c];
    sO1[h * CH + c] = out > 0.f ? out : 0.f;
    __syncthreads();

    // h2 = relu(o1) @ W2  (+ alpha2 scalars), one wave
    if (tid < 64) {
        float a2 = 0.f;
#pragma unroll 8
        for (int k = 0; k < D1; k++) a2 += sO1[k] * W2[k * CH + tid];
        w.h2c[b * CH + tid] = a2;
        float vs = a2 * a_s2[tid];
        float vd = a2 * a_d2[tid];
        for (int o = 32; o > 0; o >>= 1) {
            vs += __shfl_xor(vs, o, 64);
            vd += __shfl_xor(vd, o, 64);
        }
        if (tid == 0) { w.as2[b] = vs; w.ad2[b] = vd; }
    }
}

// ball-node layer-2 aggregation + MLP head
__global__ __launch_bounds__(64) void k6_final(Ws w, const float* __restrict__ b2,
                                               const float* __restrict__ fc1w,
                                               const float* __restrict__ fc1b,
                                               const float* __restrict__ fc2w,
                                               const float* __restrict__ fc2b,
                                               float* __restrict__ out, int ball) {
    int j = threadIdx.x;
    int ne = min(w.meta[2], CAPE0);
    float adv = w.ad2[0];  // inv1[ball] == 0

    float m = -1e30f;
    for (int i = j; i <= ne; i += 64) {
        int s = (i < ne) ? w.e0[i] : ball;
        float e = w.as2[w.inv1[s]] + adv;
        e = e > 0.f ? e : NEG_SLOPE * e;
        m = fmaxf(m, e);
    }
    for (int o = 32; o > 0; o >>= 1) m = fmaxf(m, __shfl_xor(m, o, 64));

    float ss = 0.f;
    for (int i = j; i <= ne; i += 64) {
        int s = (i < ne) ? w.e0[i] : ball;
        float e = w.as2[w.inv1[s]] + adv;
        e = e > 0.f ? e : NEG_SLOPE * e;
        ss += expf(e - m);
    }
    for (int o = 32; o > 0; o >>= 1) ss += __shfl_xor(ss, o, 64);

    float acc = 0.f;  // lane j = channel
    for (int i = 0; i <= ne; i++) {
        int s = (i < ne) ? w.e0[i] : ball;
        int i1 = w.inv1[s];
        float e = w.as2[i1] + adv;
        e = e > 0.f ? e : NEG_SLOPE * e;
        acc += expf(e - m) * w.h2c[i1 * CH + j];
    }
    float bv = acc / (ss + 1e-16f) + b2[j];
    bv = bv > 0.f ? bv : 0.f;

    __shared__ float ball_v[CH];
    __shared__ float z[32];
    ball_v[j] = bv;
    __syncthreads();
    if (j < 32) {
        float a = fc1b[j];
        for (int c = 0; c < CH; c++) a += ball_v[c] * fc1w[c * 32 + j];
        z[j] = a > 0.f ? a : 0.f;
    }
    __syncthreads();
    if (j < 2) {
        float a = fc2b[j];
        for (int k = 0; k < 32; k++) a += z[k] * fc2w[k * 2 + j];
        out[j] = a;
    }
}

extern "C" void kernel_launch(void* const* d_in, const int* in_sizes, int n_in,
                              void* d_out, int out_size, void* d_ws, size_t ws_size,
                              hipStream_t stream) {
    const float* x    = (const float*)d_in[0];
    const int*   ei   = (const int*)d_in[1];
    const float* W1   = (const float*)d_in[2];
    const float* as1w = (const float*)d_in[3];
    const float* ad1w = (const float*)d_in[4];
    const float* b1   = (const float*)d_in[5];
    const float* W2   = (const float*)d_in[6];
    const float* as2w = (const float*)d_in[7];
    const float* ad2w = (const float*)d_in[8];
    const float* b2   = (const float*)d_in[9];
    const float* fc1w = (const float*)d_in[10];
    const float* fc1b = (const float*)d_in[11];
    const float* fc2w = (const float*)d_in[12];
    const float* fc2b = (const float*)d_in[13];

    int E = in_sizes[1] / 2;
    int N = in_sizes[0] / F_IN;
    int ball = N - 1;
    const int* srcA = ei;
    const int* dstA = ei + E;

    char* p = (char*)d_ws;
    auto carve = [&](size_t bytes) {
        void* r = (void*)p;
        p += (bytes + 255) & ~(size_t)255;
        return r;
    };
    Ws w;
    w.meta  = (int*)carve(16 * sizeof(int));
    w.flag1 = (int*)carve((size_t)N * sizeof(int));
    w.flag2 = (int*)carve((size_t)N * sizeof(int));
    w.inv1  = (int*)carve((size_t)N * sizeof(int));
    w.inv2  = (int*)carve((size_t)N * sizeof(int));
    w.list1 = (int*)carve(CAP1 * sizeof(int));
    w.list2 = (int*)carve(CAP2 * sizeof(int));
    w.e0    = (int*)carve(CAPE0 * sizeof(int));
    w.deg   = (int*)carve(CAP1 * sizeof(int));
    w.nbr   = (int*)carve((size_t)CAP1 * MAXDEG * sizeof(int));
    w.H1c   = (float*)carve((size_t)CAP2 * D1 * sizeof(float));
    w.as1   = (float*)carve((size_t)CAP2 * HEADS * sizeof(float));
    w.ad1   = (float*)carve((size_t)CAP2 * HEADS * sizeof(float));
    w.h2c   = (float*)carve((size_t)CAP1 * CH * sizeof(float));
    w.as2   = (float*)carve(CAP1 * sizeof(float));
    w.ad2   = (float*)carve(CAP1 * sizeof(float));

    int gE4 = (E / 4 + 255) / 256;
    k0_init<<<(N + 255) / 256, 256, 0, stream>>>(w, N, ball);
    k1_ball_edges<<<gE4, 256, 0, stream>>>(w, srcA, dstA, E, ball);
    k1b_selfloops<<<(CAP1 + 255) / 256, 256, 0, stream>>>(w);
    k2_l1_edges<<<gE4, 256, 0, stream>>>(w, srcA, dstA, E);
    k3_h1<<<CAP2, 256, 0, stream>>>(w, x, W1, as1w, ad1w);
    k45_agg_h2<<<CAP1, 256, 0, stream>>>(w, b1, W2, as2w, ad2w);
    k6_final<<<1, 64, 0, stream>>>(w, b2, fc1w, fc1b, fc2w, fc2b, (float*)d_out, ball);
}